// Round 1
// baseline (80.539 us; speedup 1.0000x reference)
//
#include <hip/hip_runtime.h>

#define NH 64
#define LFULL 2048
#define LH 1025
#define PI_F 3.14159265358979323846f

// Angle constants
#define ANG_HALF 1.5339807878856412e-3f   // pi/2048  (theta/2 per freq step)
#define ANG_STEP 3.0679615757712823e-3f   // 2*pi/2048 (DFT step per l for given t)

__global__ __launch_bounds__(256) void hippo_ssk(
    const float* __restrict__ w_ri,
    const float* __restrict__ P_ri,
    const float* __restrict__ B_ri,
    const float* __restrict__ C_ri,
    const float* __restrict__ log_dt,
    float* __restrict__ out)
{
    __shared__ float pole[NH][12];   // a, b, v00r, v00i, v01r, v01i, v10r, v10i, v11r, v11i, pad, pad
    __shared__ float2 Kf[LH];        // half-spectrum k_f per head

    const int h   = blockIdx.x;
    const int tid = threadIdx.x;
    const float dt = expf(log_dt[h]);

    // ---------------- Stage 1: per-pole precompute (threads 0..63) ----------------
    if (tid < NH) {
        const float2 w = ((const float2*)w_ri)[h*NH + tid];
        const float2 P = ((const float2*)P_ri)[h*NH + tid];
        const float2 B = ((const float2*)B_ri)[h*NH + tid];
        const float2 C = ((const float2*)C_ri)[h*NH + tid];
        const float a = w.x * dt;          // Re(w*dt)
        const float b = w.y * dt;          // Im(w*dt)
        float* pp = pole[tid];
        pp[0] = a;  pp[1] = b;
        pp[2] = B.x*C.x - B.y*C.y;         // v00 = B*C
        pp[3] = B.x*C.y + B.y*C.x;
        pp[4] = B.x*P.x + B.y*P.y;         // v01 = B*conj(P)
        pp[5] = B.y*P.x - B.x*P.y;
        pp[6] = P.x*C.x - P.y*C.y;         // v10 = P*C
        pp[7] = P.x*C.y + P.y*C.x;
        pp[8] = P.x*P.x + P.y*P.y;         // v11 = P*conj(P)  (real)
        pp[9] = 0.f; pp[10] = 0.f; pp[11] = 0.f;
    }
    __syncthreads();

    // ---------------- Stage 2: Cauchy kernel -> k_f[l] ----------------
    // z_l = 2i*tan(pi*l/L) (purely imaginary); pair term:
    //   v/(z-w) + conj(v)/(z-conj(w)) with w=a+ib, z=iy:
    //   re = -(f1+f2)*vr + (e1-e2)*vi ; im = -(e1+e2)*vr + (f2-f1)*vi
    //   f=a*inv, e=(y∓b)*inv, inv=1/(a^2+(y∓b)^2)
    for (int i = 0; i < 5; ++i) {
        const int l = tid + 256*i;
        if (l >= LH) break;
        if (l == 1024) {
            // analytic limit at Nyquist: k_f = dt * Re(sum v00)
            float sum = 0.f;
            #pragma unroll
            for (int n = 0; n < NH; ++n) sum += pole[n][2];
            Kf[1024] = make_float2(dt*sum, 0.f);
        } else {
            float s0, c0;
            sincosf(ANG_HALF * (float)l, &s0, &c0);
            const float y = 2.f * s0 / c0;          // l=0 -> 0
            float r00r=0.f,r00i=0.f,r01r=0.f,r01i=0.f;
            float r10r=0.f,r10i=0.f,r11r=0.f,r11i=0.f;
            #pragma unroll 8
            for (int n = 0; n < NH; ++n) {
                const float4 p0 = *reinterpret_cast<const float4*>(&pole[n][0]);
                const float4 p1 = *reinterpret_cast<const float4*>(&pole[n][4]);
                const float2 p2 = *reinterpret_cast<const float2*>(&pole[n][8]);
                const float a = p0.x, b = p0.y;
                const float ymb = y - b, ypb = y + b;
                const float inv1 = __builtin_amdgcn_rcpf(fmaf(a, a, ymb*ymb));
                const float inv2 = __builtin_amdgcn_rcpf(fmaf(a, a, ypb*ypb));
                const float f1 = a*inv1,   f2 = a*inv2;
                const float e1 = ymb*inv1, e2 = ypb*inv2;
                const float FA = f1 + f2;   // * (-vr) -> re
                const float EB = e1 - e2;   // * ( vi) -> re
                const float EC = e1 + e2;   // * (-vr) -> im
                const float FD = f2 - f1;   // * ( vi) -> im
                r00r = fmaf(-p0.z, FA, fmaf(p0.w, EB, r00r));
                r00i = fmaf(-p0.z, EC, fmaf(p0.w, FD, r00i));
                r01r = fmaf(-p1.x, FA, fmaf(p1.y, EB, r01r));
                r01i = fmaf(-p1.x, EC, fmaf(p1.y, FD, r01i));
                r10r = fmaf(-p1.z, FA, fmaf(p1.w, EB, r10r));
                r10i = fmaf(-p1.z, EC, fmaf(p1.w, FD, r10i));
                r11r = fmaf(-p2.x, FA, fmaf(p2.y, EB, r11r));
                r11i = fmaf(-p2.x, EC, fmaf(p2.y, FD, r11i));
            }
            r00r*=dt; r00i*=dt; r01r*=dt; r01i*=dt;
            r10r*=dt; r10i*=dt; r11r*=dt; r11i*=dt;
            // Woodbury correction: corr = r01*r10/(1+r11)
            const float nr = r01r*r10r - r01i*r10i;
            const float ni = r01r*r10i + r01i*r10r;
            const float dr = 1.f + r11r, di = r11i;
            const float id2 = 1.f / (dr*dr + di*di);
            const float cr = (nr*dr + ni*di)*id2;
            const float ci = (ni*dr - nr*di)*id2;
            const float k0r = r00r - cr, k0i = r00i - ci;
            // * 2/(1+omega) = (1 + i*y/2)
            const float hy = 0.5f*y;
            Kf[l] = make_float2(k0r - k0i*hy, k0i + k0r*hy);
        }
    }
    __syncthreads();

    // ---------------- Stage 3: irfft via half-spectrum real DFT ----------------
    // k[t] = (1/L)[K0r + (-1)^t KNr + 2*sum_{l=1}^{1023} (Kr cos - Ki sin)(2*pi*l*t/L)]
    // Each thread: t0=tid, t1=tid+256; each covers 4 outputs t+512j via i^l quarter turns.
    const float K0r = Kf[0].x;
    const float KNr = Kf[1024].x;
    const int t0 = tid;
    const int t1 = tid + 256;
    const float sgn = (tid & 1) ? -1.f : 1.f;
    const float inita = 0.5f*K0r + 0.5f*sgn*KNr;
    float a0=inita, a1=inita, a2=inita, a3=inita;
    float b0=inita, b1=inita, b2=inita, b3=inita;

    float c0, s0, c1, s1;
    sincosf(ANG_STEP*(float)t0, &s0, &c0);   // angle for l=1 (also the step)
    sincosf(ANG_STEP*(float)t1, &s1, &c1);
    const float cr0=c0, sr0=s0, cr1=c1, sr1=s1;

    int l = 1;
#define BODY(CASE) do { \
        const float2 K = Kf[l]; \
        const float u0 = K.x*c0 - K.y*s0; \
        const float v0 = K.x*s0 + K.y*c0; \
        const float u1 = K.x*c1 - K.y*s1; \
        const float v1 = K.x*s1 + K.y*c1; \
        if ((CASE)==0)      { a0+=u0; a1+=u0; a2+=u0; a3+=u0; b0+=u1; b1+=u1; b2+=u1; b3+=u1; } \
        else if ((CASE)==1) { a0+=u0; a1-=v0; a2-=u0; a3+=v0; b0+=u1; b1-=v1; b2-=u1; b3+=v1; } \
        else if ((CASE)==2) { a0+=u0; a1-=u0; a2+=u0; a3-=u0; b0+=u1; b1-=u1; b2+=u1; b3-=u1; } \
        else                { a0+=u0; a1+=v0; a2-=u0; a3-=v0; b0+=u1; b1+=v1; b2-=u1; b3-=v1; } \
        { const float nc0 = c0*cr0 - s0*sr0, ns0 = s0*cr0 + c0*sr0; c0=nc0; s0=ns0; } \
        { const float nc1 = c1*cr1 - s1*sr1, ns1 = s1*cr1 + c1*sr1; c1=nc1; s1=ns1; } \
        ++l; \
    } while (0)

    BODY(1); BODY(2); BODY(3);               // l = 1,2,3
    for (int g = 0; g < 255; ++g) {          // l = 4..1023 in aligned groups of 4
        if ((l & 255) == 0) {                // exact re-sync at l = 256, 512, 768
            const int m0 = (l*t0) & 2047;
            const int m1 = (l*t1) & 2047;
            sincosf(ANG_STEP*(float)m0, &s0, &c0);
            sincosf(ANG_STEP*(float)m1, &s1, &c1);
        }
        BODY(0); BODY(1); BODY(2); BODY(3);
    }
#undef BODY

    float* op = out + (size_t)h * LFULL;
    const float sc = 1.0f/1024.0f;           // 2/L
    op[t0]        = a0*sc;
    op[t0+512]    = a1*sc;
    op[t0+1024]   = a2*sc;
    op[t0+1536]   = a3*sc;
    op[t1]        = b0*sc;
    op[t1+512]    = b1*sc;
    op[t1+1024]   = b2*sc;
    op[t1+1536]   = b3*sc;
}

extern "C" void kernel_launch(void* const* d_in, const int* in_sizes, int n_in,
                              void* d_out, int out_size, void* d_ws, size_t ws_size,
                              hipStream_t stream) {
    const float* w_ri   = (const float*)d_in[0];
    const float* P_ri   = (const float*)d_in[1];
    const float* B_ri   = (const float*)d_in[2];
    const float* C_ri   = (const float*)d_in[3];
    const float* log_dt = (const float*)d_in[4];
    float* out = (float*)d_out;
    const int Hn = in_sizes[4];   // 256 heads
    hippo_ssk<<<dim3(Hn), dim3(256), 0, stream>>>(w_ri, P_ri, B_ri, C_ri, log_dt, out);
}

// Round 2
// 22.344 us; speedup vs baseline: 3.6045x; 3.6045x over previous
//
#include <hip/hip_runtime.h>

#define NH 64
#define LFULL 2048
#define MH 1024
#define PI_F 3.14159265358979323846f
#define ANG_HALF 1.5339807878856412e-3f   // pi/2048

__global__ __launch_bounds__(512) void hippo_ssk(
    const float* __restrict__ w_ri,
    const float* __restrict__ P_ri,
    const float* __restrict__ B_ri,
    const float* __restrict__ C_ri,
    const float* __restrict__ log_dt,
    float* __restrict__ out)
{
    __shared__ float pole[NH][12];   // a, b, v00r, v00i, v01r, v01i, v10r, v10i, v11(real), pad...
    __shared__ float2 Kf[MH + 1];    // half-spectrum k_f
    __shared__ float2 bufA[MH];      // FFT ping
    __shared__ float2 bufB[MH];      // FFT pong

    const int h   = blockIdx.x;
    const int tid = threadIdx.x;
    const float dt = __expf(log_dt[h]);

    // ---------------- Stage 1: per-pole precompute (threads 0..63) ----------------
    // v-values pre-scaled by dt (equivalent to reference's r *= dt before Woodbury).
    if (tid < NH) {
        const float2 w = ((const float2*)w_ri)[h*NH + tid];
        const float2 P = ((const float2*)P_ri)[h*NH + tid];
        const float2 B = ((const float2*)B_ri)[h*NH + tid];
        const float2 C = ((const float2*)C_ri)[h*NH + tid];
        float* pp = pole[tid];
        pp[0] = w.x * dt;                       // Re(w*dt)
        pp[1] = w.y * dt;                       // Im(w*dt)
        pp[2] = (B.x*C.x - B.y*C.y) * dt;       // v00 = B*C
        pp[3] = (B.x*C.y + B.y*C.x) * dt;
        pp[4] = (B.x*P.x + B.y*P.y) * dt;       // v01 = B*conj(P)
        pp[5] = (B.y*P.x - B.x*P.y) * dt;
        pp[6] = (P.x*C.x - P.y*C.y) * dt;       // v10 = P*C
        pp[7] = (P.x*C.y + P.y*C.x) * dt;
        pp[8] = (P.x*P.x + P.y*P.y) * dt;       // v11 = |P|^2 (real)
        pp[9] = 0.f; pp[10] = 0.f; pp[11] = 0.f;
    }
    __syncthreads();

    // ---------------- Stage 2: Cauchy kernel -> Kf[l], l = tid, tid+512 ----------------
    #pragma unroll
    for (int i = 0; i < 2; ++i) {
        const int l = tid + 512*i;
        float s0, c0;
        sincosf(ANG_HALF * (float)l, &s0, &c0);   // precise: tan blows up near l=1024
        const float y = 2.f * s0 / c0;            // z = i*y, y = 2*tan(pi*l/2048)
        float r00r=0.f,r00i=0.f,r01r=0.f,r01i=0.f;
        float r10r=0.f,r10i=0.f,r11r=0.f,r11i=0.f;
        #pragma unroll 8
        for (int n = 0; n < NH; ++n) {
            const float4 p0 = *reinterpret_cast<const float4*>(&pole[n][0]);
            const float4 p1 = *reinterpret_cast<const float4*>(&pole[n][4]);
            const float v11 = pole[n][8];
            const float a = p0.x, b = p0.y;
            const float ymb = y - b, ypb = y + b;
            const float inv1 = __builtin_amdgcn_rcpf(fmaf(a, a, ymb*ymb));
            const float inv2 = __builtin_amdgcn_rcpf(fmaf(a, a, ypb*ypb));
            const float f1 = a*inv1,   f2 = a*inv2;
            const float e1 = ymb*inv1, e2 = ypb*inv2;
            const float FA = f1 + f2;   // * (-vr) -> re
            const float EB = e1 - e2;   // * ( vi) -> re
            const float EC = e1 + e2;   // * (-vr) -> im
            const float FD = f2 - f1;   // * ( vi) -> im
            r00r = fmaf(-p0.z, FA, fmaf(p0.w, EB, r00r));
            r00i = fmaf(-p0.z, EC, fmaf(p0.w, FD, r00i));
            r01r = fmaf(-p1.x, FA, fmaf(p1.y, EB, r01r));
            r01i = fmaf(-p1.x, EC, fmaf(p1.y, FD, r01i));
            r10r = fmaf(-p1.z, FA, fmaf(p1.w, EB, r10r));
            r10i = fmaf(-p1.z, EC, fmaf(p1.w, FD, r10i));
            r11r = fmaf(-v11, FA, r11r);
            r11i = fmaf(-v11, EC, r11i);
        }
        // Woodbury: k0 = r00 - r01*r10/(1+r11)
        const float nr = r01r*r10r - r01i*r10i;
        const float ni = r01r*r10i + r01i*r10r;
        const float dr = 1.f + r11r, di = r11i;
        const float id2 = 1.f / (dr*dr + di*di);
        const float cr = (nr*dr + ni*di)*id2;
        const float ci = (ni*dr - nr*di)*id2;
        const float k0r = r00r - cr, k0i = r00i - ci;
        // * 2/(1+omega) = 1 + i*y/2
        const float hy = 0.5f*y;
        Kf[l] = make_float2(k0r - k0i*hy, k0i + k0r*hy);
    }
    if (tid == 0) {
        // Nyquist bin: analytic z->inf limit: dt * Re(sum v00)  (v00 pre-scaled by dt)
        float sum = 0.f;
        #pragma unroll
        for (int n = 0; n < NH; ++n) sum += pole[n][2];
        Kf[MH] = make_float2(sum, 0.f);
    }
    __syncthreads();

    // ---------------- Stage 3a: half-spectrum -> Z[k] for complex IFFT ----------------
    // E = (X[k]+conj(X[M-k]))/2, O = e^{+i*pi*k/M}*(X[k]-conj(X[M-k]))/2, Z = E + i*O
    #pragma unroll
    for (int i = 0; i < 2; ++i) {
        const int k = tid + 512*i;
        float2 Xk = Kf[k];
        if (k == 0) Xk.y = 0.f;              // bin-0 imag ignored (rfft/halfcomplex semantics)
        float2 Xc = Kf[MH - k];
        Xc.y = -Xc.y;
        const float Er = 0.5f*(Xk.x + Xc.x), Ei = 0.5f*(Xk.y + Xc.y);
        const float Tr = 0.5f*(Xk.x - Xc.x), Ti = 0.5f*(Xk.y - Xc.y);
        const float ang = (PI_F/1024.f) * (float)k;
        const float ca = __cosf(ang), sa = __sinf(ang);
        const float Or = ca*Tr - sa*Ti;
        const float Oi = ca*Ti + sa*Tr;
        bufA[k] = make_float2(Er - Oi, Ei + Or);
    }
    __syncthreads();

    // ---------------- Stage 3b: 1024-pt radix-2 Stockham inverse FFT ----------------
    // z[n] = (1/M) * sum_k Z[k] e^{+2pi i k n / M}; self-sorting, ping-pong LDS.
    float2* Xb = bufA;
    float2* Yb = bufB;
    int m = 1;
    #pragma unroll
    for (int st = 0; st < 10; ++st) {
        const int jm = tid & ~(m - 1);                 // j*m
        const float ang = (PI_F/512.f) * (float)jm;    // +pi*j/l, inverse sign
        const float cw = __cosf(ang), sw = __sinf(ang);
        const float2 c0 = Xb[tid];
        const float2 c1 = Xb[tid + 512];
        const int o0 = tid + jm;
        const float drr = c0.x - c1.x, dii = c0.y - c1.y;
        Yb[o0]     = make_float2(c0.x + c1.x, c0.y + c1.y);
        Yb[o0 + m] = make_float2(cw*drr - sw*dii, cw*dii + sw*drr);
        __syncthreads();
        float2* t = Xb; Xb = Yb; Yb = t;
        m <<= 1;
    }

    // ---------------- Stage 3c: interleave + store: x[2n]=Re z[n], x[2n+1]=Im z[n] ----------------
    const float sc = 1.0f/1024.0f;
    float2* op2 = (float2*)(out + (size_t)h * LFULL);
    const float2 z0 = Xb[tid];
    op2[tid]       = make_float2(z0.x*sc, z0.y*sc);
    const float2 z1 = Xb[tid + 512];
    op2[tid + 512] = make_float2(z1.x*sc, z1.y*sc);
}

extern "C" void kernel_launch(void* const* d_in, const int* in_sizes, int n_in,
                              void* d_out, int out_size, void* d_ws, size_t ws_size,
                              hipStream_t stream) {
    const float* w_ri   = (const float*)d_in[0];
    const float* P_ri   = (const float*)d_in[1];
    const float* B_ri   = (const float*)d_in[2];
    const float* C_ri   = (const float*)d_in[3];
    const float* log_dt = (const float*)d_in[4];
    float* out = (float*)d_out;
    const int Hn = in_sizes[4];   // 256 heads
    hippo_ssk<<<dim3(Hn), dim3(512), 0, stream>>>(w_ri, P_ri, B_ri, C_ri, log_dt, out);
}

// Round 3
// 22.005 us; speedup vs baseline: 3.6600x; 1.0154x over previous
//
#include <hip/hip_runtime.h>

#define NH 64
#define LFULL 2048
#define MH 1024
#define PI_F 3.14159265358979323846f
#define ANG_HALF 1.5339807878856412e-3f   // pi/2048

__global__ __launch_bounds__(1024) void hippo_ssk(
    const float* __restrict__ w_ri,
    const float* __restrict__ P_ri,
    const float* __restrict__ B_ri,
    const float* __restrict__ C_ri,
    const float* __restrict__ log_dt,
    float* __restrict__ out)
{
    __shared__ float pole[NH][12];   // a, b, v00r, v00i, v01r, v01i, v10r, v10i, v11(real), pad
    __shared__ float2 Kf[MH + 1];    // half-spectrum k_f
    __shared__ float2 bufA[MH];      // FFT ping
    __shared__ float2 bufB[MH];      // FFT pong

    const int h   = blockIdx.x;
    const int tid = threadIdx.x;
    const float dt = __expf(log_dt[h]);

    // ---------------- Stage 1: per-pole precompute (wave 0, threads 0..63) ----------------
    // v-values pre-scaled by dt (equivalent to reference's r *= dt before Woodbury).
    if (tid < NH) {
        const float2 w = ((const float2*)w_ri)[h*NH + tid];
        const float2 P = ((const float2*)P_ri)[h*NH + tid];
        const float2 B = ((const float2*)B_ri)[h*NH + tid];
        const float2 C = ((const float2*)C_ri)[h*NH + tid];
        float* pp = pole[tid];
        const float v00r = (B.x*C.x - B.y*C.y) * dt;
        pp[0] = w.x * dt;                       // Re(w*dt)
        pp[1] = w.y * dt;                       // Im(w*dt)
        pp[2] = v00r;                           // v00 = B*C
        pp[3] = (B.x*C.y + B.y*C.x) * dt;
        pp[4] = (B.x*P.x + B.y*P.y) * dt;       // v01 = B*conj(P)
        pp[5] = (B.y*P.x - B.x*P.y) * dt;
        pp[6] = (P.x*C.x - P.y*C.y) * dt;       // v10 = P*C
        pp[7] = (P.x*C.y + P.y*C.x) * dt;
        pp[8] = (P.x*P.x + P.y*P.y) * dt;       // v11 = |P|^2 (real)
        pp[9] = 0.f; pp[10] = 0.f; pp[11] = 0.f;
        // Nyquist bin (z->inf limit): Re(sum v00). Wave-level reduce.
        float sum = v00r;
        #pragma unroll
        for (int off = 32; off > 0; off >>= 1) sum += __shfl_down(sum, off, 64);
        if (tid == 0) Kf[MH] = make_float2(sum, 0.f);
    }
    __syncthreads();

    // ---------------- Stage 2: Cauchy kernel -> Kf[l], l = tid ----------------
    {
        const int l = tid;
        float s0, c0;
        sincosf(ANG_HALF * (float)l, &s0, &c0);   // precise: tan blows up near l=1024
        const float y = 2.f * s0 / c0;            // z = i*y, y = 2*tan(pi*l/2048)
        float r00r=0.f,r00i=0.f,r01r=0.f,r01i=0.f;
        float r10r=0.f,r10i=0.f,r11r=0.f,r11i=0.f;
        #pragma unroll 8
        for (int n = 0; n < NH; ++n) {
            const float4 p0 = *reinterpret_cast<const float4*>(&pole[n][0]);
            const float4 p1 = *reinterpret_cast<const float4*>(&pole[n][4]);
            const float v11 = pole[n][8];
            const float a = p0.x, b = p0.y;
            const float ymb = y - b, ypb = y + b;
            const float inv1 = __builtin_amdgcn_rcpf(fmaf(a, a, ymb*ymb));
            const float inv2 = __builtin_amdgcn_rcpf(fmaf(a, a, ypb*ypb));
            const float f1 = a*inv1,   f2 = a*inv2;
            const float e1 = ymb*inv1, e2 = ypb*inv2;
            const float FA = f1 + f2;   // * (-vr) -> re
            const float EB = e1 - e2;   // * ( vi) -> re
            const float EC = e1 + e2;   // * (-vr) -> im
            const float FD = f2 - f1;   // * ( vi) -> im
            r00r = fmaf(-p0.z, FA, fmaf(p0.w, EB, r00r));
            r00i = fmaf(-p0.z, EC, fmaf(p0.w, FD, r00i));
            r01r = fmaf(-p1.x, FA, fmaf(p1.y, EB, r01r));
            r01i = fmaf(-p1.x, EC, fmaf(p1.y, FD, r01i));
            r10r = fmaf(-p1.z, FA, fmaf(p1.w, EB, r10r));
            r10i = fmaf(-p1.z, EC, fmaf(p1.w, FD, r10i));
            r11r = fmaf(-v11, FA, r11r);
            r11i = fmaf(-v11, EC, r11i);
        }
        // Woodbury: k0 = r00 - r01*r10/(1+r11)
        const float nr = r01r*r10r - r01i*r10i;
        const float ni = r01r*r10i + r01i*r10r;
        const float dr = 1.f + r11r, di = r11i;
        const float id2 = 1.f / (dr*dr + di*di);
        const float cr = (nr*dr + ni*di)*id2;
        const float ci = (ni*dr - nr*di)*id2;
        const float k0r = r00r - cr, k0i = r00i - ci;
        // * 2/(1+omega) = 1 + i*y/2
        const float hy = 0.5f*y;
        Kf[l] = make_float2(k0r - k0i*hy, k0i + k0r*hy);
    }
    __syncthreads();

    // ---------------- Stage 3a: half-spectrum -> Z[k] for complex IFFT ----------------
    // E = (X[k]+conj(X[M-k]))/2, O = e^{+i*pi*k/M}*(X[k]-conj(X[M-k]))/2, Z = E + i*O
    {
        const int k = tid;
        float2 Xk = Kf[k];
        if (k == 0) Xk.y = 0.f;              // bin-0 imag ignored (halfcomplex semantics)
        float2 Xc = Kf[MH - k];
        Xc.y = -Xc.y;
        const float Er = 0.5f*(Xk.x + Xc.x), Ei = 0.5f*(Xk.y + Xc.y);
        const float Tr = 0.5f*(Xk.x - Xc.x), Ti = 0.5f*(Xk.y - Xc.y);
        const float ang = (PI_F/1024.f) * (float)k;
        float sa, ca;
        __sincosf(ang, &sa, &ca);
        const float Or = ca*Tr - sa*Ti;
        const float Oi = ca*Ti + sa*Tr;
        bufA[k] = make_float2(Er - Oi, Ei + Or);
    }
    __syncthreads();

    // ---------------- Stage 3b: 1024-pt radix-2 Stockham inverse FFT ----------------
    // All 1024 threads: each computes ONE output point per stage.
    // Butterfly j (=jm/m): in = X[jm+r], X[jm+r+512]; out[2jm+r] = sum, out[2jm+m+r] = w*diff.
    float2* Xb = bufA;
    float2* Yb = bufB;
    int m = 1;
    #pragma unroll
    for (int st = 0; st < 10; ++st) {
        const int o  = tid;
        const int r  = o & (m - 1);
        const int hi = o & m;                    // 0 -> sum output, else twiddled diff
        const int jm = (o >> 1) & ~(m - 1);      // j*m
        const int ti = jm + r;
        const float2 c0 = Xb[ti];
        const float2 c1 = Xb[ti + 512];
        const float ang = (PI_F/512.f) * (float)jm;   // inverse FFT: +angle
        float sw, cw;
        __sincosf(ang, &sw, &cw);
        const float dr = c0.x - c1.x, di = c0.y - c1.y;
        const float tr = cw*dr - sw*di, tii = cw*di + sw*dr;
        const float2 res = hi ? make_float2(tr, tii)
                              : make_float2(c0.x + c1.x, c0.y + c1.y);
        Yb[o] = res;
        __syncthreads();
        float2* t = Xb; Xb = Yb; Yb = t;
        m <<= 1;
    }

    // ---------------- Stage 3c: interleave + store: x[2n]=Re z[n], x[2n+1]=Im z[n] ----------------
    const float sc = 1.0f/1024.0f;
    float2* op2 = (float2*)(out + (size_t)h * LFULL);
    const float2 z = Xb[tid];
    op2[tid] = make_float2(z.x*sc, z.y*sc);
}

extern "C" void kernel_launch(void* const* d_in, const int* in_sizes, int n_in,
                              void* d_out, int out_size, void* d_ws, size_t ws_size,
                              hipStream_t stream) {
    const float* w_ri   = (const float*)d_in[0];
    const float* P_ri   = (const float*)d_in[1];
    const float* B_ri   = (const float*)d_in[2];
    const float* C_ri   = (const float*)d_in[3];
    const float* log_dt = (const float*)d_in[4];
    float* out = (float*)d_out;
    const int Hn = in_sizes[4];   // 256 heads
    hippo_ssk<<<dim3(Hn), dim3(1024), 0, stream>>>(w_ri, P_ri, B_ri, C_ri, log_dt, out);
}

// Round 4
// 21.942 us; speedup vs baseline: 3.6705x; 1.0029x over previous
//
#include <hip/hip_runtime.h>

#define NH 64
#define LFULL 2048
#define MH 1024
#define PI_F 3.14159265358979323846f
#define ANG_HALF 1.5339807878856412e-3f   // pi/2048

struct Acc { float r00r, r00i, r01r, r01i, r10r, r10i, r11r, r11i; };

// One pole's contribution at z = i*y into accumulator AC. p0=(a,b,v00r,v00i),
// p1=(v01r,v01i,v10r,v10i), v11 real. All v pre-scaled by dt.
#define CAUCHY_STEP(Y, AC) do {                                          \
    const float ymb = (Y) - b, ypb = (Y) + b;                            \
    const float inv1 = __builtin_amdgcn_rcpf(fmaf(a, a, ymb*ymb));       \
    const float inv2 = __builtin_amdgcn_rcpf(fmaf(a, a, ypb*ypb));       \
    const float f1 = a*inv1,   f2 = a*inv2;                              \
    const float e1 = ymb*inv1, e2 = ypb*inv2;                            \
    const float FA = f1 + f2;                                            \
    const float EB = e1 - e2;                                            \
    const float EC = e1 + e2;                                            \
    const float FD = f2 - f1;                                            \
    AC.r00r = fmaf(-p0.z, FA, fmaf(p0.w, EB, AC.r00r));                  \
    AC.r00i = fmaf(-p0.z, EC, fmaf(p0.w, FD, AC.r00i));                  \
    AC.r01r = fmaf(-p1.x, FA, fmaf(p1.y, EB, AC.r01r));                  \
    AC.r01i = fmaf(-p1.x, EC, fmaf(p1.y, FD, AC.r01i));                  \
    AC.r10r = fmaf(-p1.z, FA, fmaf(p1.w, EB, AC.r10r));                  \
    AC.r10i = fmaf(-p1.z, EC, fmaf(p1.w, FD, AC.r10i));                  \
    AC.r11r = fmaf(-v11, FA, AC.r11r);                                   \
    AC.r11i = fmaf(-v11, EC, AC.r11i);                                   \
} while (0)

__global__ __launch_bounds__(512) void hippo_ssk(
    const float* __restrict__ w_ri,
    const float* __restrict__ P_ri,
    const float* __restrict__ B_ri,
    const float* __restrict__ C_ri,
    const float* __restrict__ log_dt,
    float* __restrict__ out)
{
    __shared__ float pole[NH][12];   // a, b, v00r, v00i, v01r, v01i, v10r, v10i, v11(real), pad
    __shared__ float2 Kf[MH + 1];    // half-spectrum k_f
    __shared__ float2 bufA[MH];      // FFT ping
    __shared__ float2 bufB[MH];      // FFT pong

    const int h   = blockIdx.x;
    const int tid = threadIdx.x;
    const float dt = __expf(log_dt[h]);

    // ---------------- Stage 1: per-pole precompute (wave 0, threads 0..63) ----------------
    if (tid < NH) {
        const float2 w = ((const float2*)w_ri)[h*NH + tid];
        const float2 P = ((const float2*)P_ri)[h*NH + tid];
        const float2 B = ((const float2*)B_ri)[h*NH + tid];
        const float2 C = ((const float2*)C_ri)[h*NH + tid];
        float* pp = pole[tid];
        const float v00r = (B.x*C.x - B.y*C.y) * dt;
        pp[0] = w.x * dt;                       // Re(w*dt)
        pp[1] = w.y * dt;                       // Im(w*dt)
        pp[2] = v00r;                           // v00 = B*C
        pp[3] = (B.x*C.y + B.y*C.x) * dt;
        pp[4] = (B.x*P.x + B.y*P.y) * dt;       // v01 = B*conj(P)
        pp[5] = (B.y*P.x - B.x*P.y) * dt;
        pp[6] = (P.x*C.x - P.y*C.y) * dt;       // v10 = P*C
        pp[7] = (P.x*C.y + P.y*C.x) * dt;
        pp[8] = (P.x*P.x + P.y*P.y) * dt;       // v11 = |P|^2 (real)
        pp[9] = 0.f; pp[10] = 0.f; pp[11] = 0.f;
        // Nyquist bin (z->inf limit): Re(sum v00). Wave-level reduce.
        float sum = v00r;
        #pragma unroll
        for (int off = 32; off > 0; off >>= 1) sum += __shfl_down(sum, off, 64);
        if (tid == 0) Kf[MH] = make_float2(sum, 0.f);
    }
    __syncthreads();

    // ---------------- Stage 2: Cauchy kernel, pole-outer / 2-freq-inner ----------------
    {
        const int lA = tid;
        const int lB = tid + 512;
        float sA, cA, sB, cB;
        sincosf(ANG_HALF * (float)lA, &sA, &cA);   // precise: tan blows up near l=1024
        sincosf(ANG_HALF * (float)lB, &sB, &cB);
        const float yA = 2.f * sA / cA;            // z = i*y, y = 2*tan(pi*l/2048)
        const float yB = 2.f * sB / cB;
        Acc A = {0.f,0.f,0.f,0.f,0.f,0.f,0.f,0.f};
        Acc Bq = {0.f,0.f,0.f,0.f,0.f,0.f,0.f,0.f};
        #pragma unroll 4
        for (int n = 0; n < NH; ++n) {
            const float4 p0 = *reinterpret_cast<const float4*>(&pole[n][0]);
            const float4 p1 = *reinterpret_cast<const float4*>(&pole[n][4]);
            const float v11 = pole[n][8];
            const float a = p0.x, b = p0.y;
            CAUCHY_STEP(yA, A);
            CAUCHY_STEP(yB, Bq);
        }
        // Woodbury + spectral twist for both freqs
        #define FINISH(AC, Y, L) do {                                        \
            const float nr = AC.r01r*AC.r10r - AC.r01i*AC.r10i;              \
            const float ni = AC.r01r*AC.r10i + AC.r01i*AC.r10r;              \
            const float dr = 1.f + AC.r11r, di = AC.r11i;                    \
            const float id2 = 1.f / (dr*dr + di*di);                         \
            const float cr = (nr*dr + ni*di)*id2;                            \
            const float ci = (ni*dr - nr*di)*id2;                            \
            const float k0r = AC.r00r - cr, k0i = AC.r00i - ci;              \
            const float hy = 0.5f*(Y);                                       \
            Kf[(L)] = make_float2(k0r - k0i*hy, k0i + k0r*hy);               \
        } while (0)
        FINISH(A, yA, lA);
        FINISH(Bq, yB, lB);
        #undef FINISH
    }
    __syncthreads();

    // ---------------- Stage 3a: half-spectrum -> Z[k] for complex IFFT ----------------
    // E = (X[k]+conj(X[M-k]))/2, O = e^{+i*pi*k/M}*(X[k]-conj(X[M-k]))/2, Z = E + i*O
    #pragma unroll
    for (int i = 0; i < 2; ++i) {
        const int k = tid + 512*i;
        float2 Xk = Kf[k];
        if (k == 0) Xk.y = 0.f;              // bin-0 imag ignored (halfcomplex semantics)
        float2 Xc = Kf[MH - k];
        Xc.y = -Xc.y;
        const float Er = 0.5f*(Xk.x + Xc.x), Ei = 0.5f*(Xk.y + Xc.y);
        const float Tr = 0.5f*(Xk.x - Xc.x), Ti = 0.5f*(Xk.y - Xc.y);
        const float ang = (PI_F/1024.f) * (float)k;
        float sa, ca;
        __sincosf(ang, &sa, &ca);
        const float Or = ca*Tr - sa*Ti;
        const float Oi = ca*Ti + sa*Tr;
        bufA[k] = make_float2(Er - Oi, Ei + Or);
    }
    __syncthreads();

    // ---------------- Stage 3b: 1024-pt radix-2 Stockham inverse FFT ----------------
    float2* Xb = bufA;
    float2* Yb = bufB;
    int m = 1;
    #pragma unroll
    for (int st = 0; st < 10; ++st) {
        const int jm = tid & ~(m - 1);                 // j*m
        const float ang = (PI_F/512.f) * (float)jm;    // inverse FFT: +angle
        float sw, cw;
        __sincosf(ang, &sw, &cw);
        const float2 c0 = Xb[tid];
        const float2 c1 = Xb[tid + 512];
        const int o0 = tid + jm;
        const float drr = c0.x - c1.x, dii = c0.y - c1.y;
        Yb[o0]     = make_float2(c0.x + c1.x, c0.y + c1.y);
        Yb[o0 + m] = make_float2(cw*drr - sw*dii, cw*dii + sw*drr);
        __syncthreads();
        float2* t = Xb; Xb = Yb; Yb = t;
        m <<= 1;
    }

    // ---------------- Stage 3c: interleave + store: x[2n]=Re z[n], x[2n+1]=Im z[n] ----------------
    const float sc = 1.0f/1024.0f;
    float2* op2 = (float2*)(out + (size_t)h * LFULL);
    const float2 z0 = Xb[tid];
    op2[tid]       = make_float2(z0.x*sc, z0.y*sc);
    const float2 z1 = Xb[tid + 512];
    op2[tid + 512] = make_float2(z1.x*sc, z1.y*sc);
}

extern "C" void kernel_launch(void* const* d_in, const int* in_sizes, int n_in,
                              void* d_out, int out_size, void* d_ws, size_t ws_size,
                              hipStream_t stream) {
    const float* w_ri   = (const float*)d_in[0];
    const float* P_ri   = (const float*)d_in[1];
    const float* B_ri   = (const float*)d_in[2];
    const float* C_ri   = (const float*)d_in[3];
    const float* log_dt = (const float*)d_in[4];
    float* out = (float*)d_out;
    const int Hn = in_sizes[4];   // 256 heads
    hippo_ssk<<<dim3(Hn), dim3(512), 0, stream>>>(w_ri, P_ri, B_ri, C_ri, log_dt, out);
}